// Round 1
// baseline (1117.473 us; speedup 1.0000x reference)
//
#include <hip/hip_runtime.h>
#include <cstdint>

#define EPSF 1e-15f
#define MAXN (1.0f - 1e-5f)

__device__ __forceinline__ float wsum64(float v) {
    v += __shfl_xor(v, 1);
    v += __shfl_xor(v, 2);
    v += __shfl_xor(v, 4);
    v += __shfl_xor(v, 8);
    v += __shfl_xor(v, 16);
    v += __shfl_xor(v, 32);
    return v;
}

// One wave (64 lanes) per KG edge; lane = embedding dim.
__global__ void kg_edge_k(const float* __restrict__ ent,
                          const float* __restrict__ rel,
                          const int* __restrict__ src,
                          const int* __restrict__ dst,
                          const int* __restrict__ typ,
                          float* __restrict__ sum,
                          int* __restrict__ cnt,
                          int nE) {
    int e = blockIdx.x * (blockDim.x >> 6) + (threadIdx.x >> 6);
    if (e >= nE) return;                     // wave-uniform
    int l = threadIdx.x & 63;
    int s = src[e], d = dst[e], t = typ[e] + 2;

    float es = ent[(size_t)s * 64 + l];
    float ed = ent[(size_t)d * 64 + l];
    float rl = rel[(size_t)t * 64 + l];

    // p = expmap0(es)
    float e2 = wsum64(es * es);
    float n0 = sqrtf(fmaxf(e2, EPSF));
    float p  = tanhf(n0) * es / n0;
    float p2 = wsum64(p * p);
    float om_p2 = 1.0f - p2;
    float lam = 2.0f / fmaxf(om_p2, EPSF);

    // dh = expmap(ed, p)
    float nd = sqrtf(fmaxf(wsum64(ed * ed), EPSF));
    float wd = tanhf(0.5f * lam * nd) * ed / nd;
    float wd2 = wsum64(wd * wd);
    float pwd = wsum64(p * wd);
    float dh = ((1.f + 2.f * pwd + wd2) * p + om_p2 * wd)
             / fmaxf(1.f + 2.f * pwd + p2 * wd2, EPSF);

    // rh = expmap(rl, p)
    float nr = sqrtf(fmaxf(wsum64(rl * rl), EPSF));
    float wr = tanhf(0.5f * lam * nr) * rl / nr;
    float wr2 = wsum64(wr * wr);
    float pwr = wsum64(p * wr);
    float rh = ((1.f + 2.f * pwr + wr2) * p + om_p2 * wr)
             / fmaxf(1.f + 2.f * pwr + p2 * wr2, EPSF);

    // z = project(mobius_add(dh, rh))
    float x2 = wsum64(dh * dh);
    float y2 = wsum64(rh * rh);
    float xy = wsum64(dh * rh);
    float z = ((1.f + 2.f * xy + y2) * dh + (1.f - x2) * rh)
            / fmaxf(1.f + 2.f * xy + x2 * y2, EPSF);
    float z2 = wsum64(z * z);
    float nz = sqrtf(fmaxf(z2, EPSF));
    if (nz > MAXN) { float sc = MAXN / nz; z *= sc; z2 *= sc * sc; }

    // tan = logmap(z, p): sub = mobius_add(-p, z)
    float mxy = wsum64(-p * z);
    float sub = ((1.f + 2.f * mxy + z2) * (-p) + om_p2 * z)
              / fmaxf(1.f + 2.f * mxy + p2 * z2, EPSF);
    float ns = sqrtf(fmaxf(wsum64(sub * sub), EPSF));
    float res = (2.f / lam) * atanhf(fminf(ns, MAXN)) * sub / ns;

    atomicAdd(&sum[(size_t)s * 64 + l], res);
    if (l == 0) atomicAdd(&cnt[s], 1);
}

// out = sum / max(cnt,1); rows < n_items -> out_items chunk, rows >= n_items -> final chunk
__global__ void out_div_k(const float* __restrict__ sum, const int* __restrict__ cnt,
                          float* __restrict__ d_final, float* __restrict__ d_items,
                          int n_items, long total) {
    long idx = (long)blockIdx.x * blockDim.x + threadIdx.x;
    if (idx >= total) return;
    int i = (int)(idx >> 6);
    float v = sum[idx] / (float)max(cnt[i], 1);
    if (i < n_items) d_items[idx] = v;
    else             d_final[idx] = v;
}

// norm_all[j] = sum_d cat_nodes[j,d]^2 ; wave per node
__global__ void norm_k(const float* __restrict__ items, const float* __restrict__ user,
                       float* __restrict__ normv, int n_items, int N) {
    int j = blockIdx.x * (blockDim.x >> 6) + (threadIdx.x >> 6);
    if (j >= N) return;
    int l = threadIdx.x & 63;
    float c = (j < n_items) ? items[(size_t)j * 64 + l]
                            : user[(size_t)(j - n_items) * 64 + l];
    float s = wsum64(c * c);
    if (l == 0) normv[j] = s;
}

// item->user pass: accumulate cat_nodes[iu_src] at iu_dst (only user rows kept)
__global__ void iu_k(const float* __restrict__ items, const float* __restrict__ user,
                     const int* __restrict__ srcA, const int* __restrict__ dstA,
                     float* __restrict__ usum, int* __restrict__ ucnt,
                     int n_items, int N, int nE) {
    int e = blockIdx.x * (blockDim.x >> 6) + (threadIdx.x >> 6);
    if (e >= nE) return;
    int s = srcA[e], d = dstA[e];
    if (d < n_items || d >= N) return;       // only user slice is output
    int l = threadIdx.x & 63;
    float v = (s < n_items) ? items[(size_t)s * 64 + l]
                            : user[(size_t)(s - n_items) * 64 + l];
    atomicAdd(&usum[(size_t)(d - n_items) * 64 + l], v);
    if (l == 0) atomicAdd(&ucnt[d - n_items], 1);
}

// user->item pass: msg = cat[s]/(norm[s]+1e-6) * norm[d], accumulate at item d
__global__ void ui_k(const float* __restrict__ items, const float* __restrict__ user,
                     const float* __restrict__ normv,
                     const int* __restrict__ srcA, const int* __restrict__ dstA,
                     float* __restrict__ isum, int* __restrict__ icnt,
                     int n_items, int nE) {
    int e = blockIdx.x * (blockDim.x >> 6) + (threadIdx.x >> 6);
    if (e >= nE) return;
    int s = srcA[e], d = dstA[e];
    if (d >= n_items) return;                // only item slice is output
    int l = threadIdx.x & 63;
    float v = (s < n_items) ? items[(size_t)s * 64 + l]
                            : user[(size_t)(s - n_items) * 64 + l];
    float m = v / (normv[s] + 1e-6f) * normv[d];
    atomicAdd(&isum[(size_t)d * 64 + l], m);
    if (l == 0) atomicAdd(&icnt[d], 1);
}

__global__ void u_div_k(const float* __restrict__ usum, const int* __restrict__ ucnt,
                        float* __restrict__ uout, long total) {
    long idx = (long)blockIdx.x * blockDim.x + threadIdx.x;
    if (idx >= total) return;
    uout[idx] = usum[idx] / (float)max(ucnt[idx >> 6], 1);
}

// gate + fusion: gi = sigmoid(oi@W1.T + icf@W2.T); out = gi*oi + (1-gi)*icf
__global__ __launch_bounds__(256) void fusion_k(const float* __restrict__ items,
                         const float* __restrict__ isum, const int* __restrict__ icnt,
                         const float* __restrict__ W1, const float* __restrict__ W2,
                         float* __restrict__ outf, int n_items) {
    __shared__ float W1s[64][65];
    __shared__ float W2s[64][65];
    for (int idx = threadIdx.x; idx < 4096; idx += blockDim.x) {
        W1s[idx >> 6][idx & 63] = W1[idx];
        W2s[idx >> 6][idx & 63] = W2[idx];
    }
    __syncthreads();
    int i = blockIdx.x * (blockDim.x >> 6) + (threadIdx.x >> 6);
    if (i >= n_items) return;
    int j = threadIdx.x & 63;
    float oi = items[(size_t)i * 64 + j];
    float cf = isum[(size_t)i * 64 + j] / (float)max(icnt[i], 1);
    float acc = 0.f;
#pragma unroll 8
    for (int k = 0; k < 64; ++k) {
        acc += __shfl(oi, k) * W1s[j][k] + __shfl(cf, k) * W2s[j][k];
    }
    float g = 1.f / (1.f + expf(-acc));
    outf[(size_t)i * 64 + j] = g * oi + (1.f - g) * cf;
}

extern "C" void kernel_launch(void* const* d_in, const int* in_sizes, int n_in,
                              void* d_out, int out_size, void* d_ws, size_t ws_size,
                              hipStream_t stream) {
    const float* ent    = (const float*)d_in[0];
    const float* usr    = (const float*)d_in[1];
    const float* rel    = (const float*)d_in[2];
    const float* W1     = (const float*)d_in[3];
    const float* W2     = (const float*)d_in[4];
    const int*   kg_src = (const int*)d_in[5];
    const int*   kg_dst = (const int*)d_in[6];
    const int*   kg_typ = (const int*)d_in[7];
    const int*   iu_src = (const int*)d_in[8];
    const int*   iu_dst = (const int*)d_in[9];
    const int*   ui_src = (const int*)d_in[10];
    const int*   ui_dst = (const int*)d_in[11];

    const int n_ent   = in_sizes[0] / 64;
    const int n_usr   = in_sizes[1] / 64;
    const int E_kg    = in_sizes[5];
    const int E_iu    = in_sizes[8];
    const int E_ui    = in_sizes[10];
    const int n_items = (out_size - in_sizes[0] - in_sizes[1]) / 64;
    const int N       = n_items + n_usr;

    float* out_final = (float*)d_out;                        // (n_ent,64)
    float* out_u     = out_final + (size_t)n_ent * 64;       // (n_usr,64)
    float* out_items = out_u + (size_t)n_usr * 64;           // (n_items,64)

    float* ws = (float*)d_ws;
    size_t o = 0;
    float* sumkg = ws + o;          o += (size_t)n_ent * 64;
    int*   cntkg = (int*)(ws + o);  o += n_ent;
    float* usum  = ws + o;          size_t z2_start = o;
                                    o += (size_t)n_usr * 64;
    int*   ucnt  = (int*)(ws + o);  o += n_usr;
    float* isum  = ws + o;          o += (size_t)n_items * 64;
    int*   icnt  = (int*)(ws + o);  o += n_items;
    float* normv = ws + o;          o += N;
    size_t z2_len = ((size_t)n_usr * 65 + (size_t)n_items * 65) * sizeof(float);

    // zero KG accumulators (sum + cnt are contiguous)
    hipMemsetAsync(sumkg, 0, ((size_t)n_ent * 65) * sizeof(float), stream);

    kg_edge_k<<<(E_kg + 3) / 4, 256, 0, stream>>>(ent, rel, kg_src, kg_dst, kg_typ,
                                                  sumkg, cntkg, E_kg);
    out_div_k<<<(int)(((size_t)n_ent * 64 + 255) / 256), 256, 0, stream>>>(
        sumkg, cntkg, out_final, out_items, n_items, (long)n_ent * 64);

    norm_k<<<(N + 3) / 4, 256, 0, stream>>>(out_items, usr, normv, n_items, N);

    // zero CF accumulators (usum,ucnt,isum,icnt contiguous)
    hipMemsetAsync(ws + z2_start, 0, z2_len, stream);

    iu_k<<<(E_iu + 3) / 4, 256, 0, stream>>>(out_items, usr, iu_src, iu_dst,
                                             usum, ucnt, n_items, N, E_iu);
    ui_k<<<(E_ui + 3) / 4, 256, 0, stream>>>(out_items, usr, normv, ui_src, ui_dst,
                                             isum, icnt, n_items, E_ui);
    u_div_k<<<(int)(((size_t)n_usr * 64 + 255) / 256), 256, 0, stream>>>(
        usum, ucnt, out_u, (long)n_usr * 64);
    fusion_k<<<(n_items + 3) / 4, 256, 0, stream>>>(out_items, isum, icnt,
                                                    W1, W2, out_final, n_items);
}

// Round 2
// 744.904 us; speedup vs baseline: 1.5002x; 1.5002x over previous
//
#include <hip/hip_runtime.h>
#include <cstdint>

#define EPSF 1e-15f
#define MAXN (1.0f - 1e-5f)

__device__ __forceinline__ float wsum64(float v) {
    v += __shfl_xor(v, 1);
    v += __shfl_xor(v, 2);
    v += __shfl_xor(v, 4);
    v += __shfl_xor(v, 8);
    v += __shfl_xor(v, 16);
    v += __shfl_xor(v, 32);
    return v;
}

// Thread-per-edge: 6 raw dot products -> full scalar hyperbolic chain -> (a,b,c)
// res = a*u + b*v + c*r  where u=ent[src], v=ent[dst], r=rel[typ+2]
__global__ void kg_coef_k(const float* __restrict__ ent,
                          const float* __restrict__ rel,
                          const int* __restrict__ src,
                          const int* __restrict__ dst,
                          const int* __restrict__ typ,
                          float4* __restrict__ coef,
                          int nE) {
    int e = blockIdx.x * blockDim.x + threadIdx.x;
    if (e >= nE) return;
    const float4* pu = (const float4*)(ent + (size_t)src[e] * 64);
    const float4* pv = (const float4*)(ent + (size_t)dst[e] * 64);
    const float4* pr = (const float4*)(rel + (size_t)(typ[e] + 2) * 64);

    float uu = 0.f, vv = 0.f, rr = 0.f, uv = 0.f, ur = 0.f, vr = 0.f;
#pragma unroll 4
    for (int i = 0; i < 16; ++i) {
        float4 a = pu[i], b = pv[i], c = pr[i];
        uu += a.x * a.x + a.y * a.y + a.z * a.z + a.w * a.w;
        vv += b.x * b.x + b.y * b.y + b.z * b.z + b.w * b.w;
        rr += c.x * c.x + c.y * c.y + c.z * c.z + c.w * c.w;
        uv += a.x * b.x + a.y * b.y + a.z * b.z + a.w * b.w;
        ur += a.x * c.x + a.y * c.y + a.z * c.z + a.w * c.w;
        vr += b.x * c.x + b.y * c.y + b.z * c.z + b.w * c.w;
    }

    // p = expmap0(u) = cp*u
    float n0 = sqrtf(fmaxf(uu, EPSF));
    float cp = tanhf(n0) / n0;
    float p2 = cp * cp * uu;
    float om_p2 = 1.f - p2;
    float lam = 2.f / fmaxf(om_p2, EPSF);

    // dh = expmap(v, p) = a1*u + b1*v
    float nv = sqrtf(fmaxf(vv, EPSF));
    float cd = tanhf(0.5f * lam * nv) / nv;
    float wd2 = cd * cd * vv;
    float pwd = cp * cd * uv;
    float Dd = fmaxf(1.f + 2.f * pwd + p2 * wd2, EPSF);
    float a1 = (1.f + 2.f * pwd + wd2) * cp / Dd;
    float b1 = om_p2 * cd / Dd;

    // rh = expmap(r, p) = a2*u + c2*r
    float nr = sqrtf(fmaxf(rr, EPSF));
    float cr = tanhf(0.5f * lam * nr) / nr;
    float wr2 = cr * cr * rr;
    float pwr = cp * cr * ur;
    float Dr = fmaxf(1.f + 2.f * pwr + p2 * wr2, EPSF);
    float a2 = (1.f + 2.f * pwr + wr2) * cp / Dr;
    float c2 = om_p2 * cr / Dr;

    // mobius_add(dh, rh): z = zu*u + zv*v + zr*r
    float x2 = a1 * a1 * uu + 2.f * a1 * b1 * uv + b1 * b1 * vv;
    float y2 = a2 * a2 * uu + 2.f * a2 * c2 * ur + c2 * c2 * rr;
    float xy = a1 * a2 * uu + a1 * c2 * ur + b1 * a2 * uv + b1 * c2 * vr;
    float den = fmaxf(1.f + 2.f * xy + x2 * y2, EPSF);
    float E = (1.f + 2.f * xy + y2) / den;
    float F = (1.f - x2) / den;
    float zu = E * a1 + F * a2;
    float zv = E * b1;
    float zr = F * c2;

    // project(z)
    float z2 = zu * zu * uu + zv * zv * vv + zr * zr * rr
             + 2.f * (zu * zv * uv + zu * zr * ur + zv * zr * vr);
    float nz = sqrtf(fmaxf(z2, EPSF));
    if (nz > MAXN) {
        float sc = MAXN / nz;
        zu *= sc; zv *= sc; zr *= sc;
        z2 *= sc * sc;
    }

    // sub = mobius_add(-p, z) = su*u + sv*v + sr*r
    float mxy = -cp * (zu * uu + zv * uv + zr * ur);
    float denl = fmaxf(1.f + 2.f * mxy + p2 * z2, EPSF);
    float G = (1.f + 2.f * mxy + z2) / denl;
    float H = om_p2 / denl;
    float su = -G * cp + H * zu;
    float sv = H * zv;
    float sr = H * zr;

    float ns2 = su * su * uu + sv * sv * vv + sr * sr * rr
              + 2.f * (su * sv * uv + su * sr * ur + sv * sr * vr);
    float ns = sqrtf(fmaxf(ns2, EPSF));
    float k = fmaxf(om_p2, EPSF) * atanhf(fminf(ns, MAXN)) / ns;

    coef[e] = make_float4(k * su, k * sv, k * sr, 0.f);
}

// Wave-per-edge: res = a*u + b*v + c*r, atomic segment-sum at src
__global__ void kg_out_k(const float* __restrict__ ent,
                         const float* __restrict__ rel,
                         const int* __restrict__ src,
                         const int* __restrict__ dst,
                         const int* __restrict__ typ,
                         const float4* __restrict__ coef,
                         float* __restrict__ sum,
                         int* __restrict__ cnt,
                         int nE) {
    int e = blockIdx.x * (blockDim.x >> 6) + (threadIdx.x >> 6);
    if (e >= nE) return;
    int l = threadIdx.x & 63;
    int s = src[e], d = dst[e], t = typ[e] + 2;
    float4 abc = coef[e];
    float res = abc.x * ent[(size_t)s * 64 + l]
              + abc.y * ent[(size_t)d * 64 + l]
              + abc.z * rel[(size_t)t * 64 + l];
    atomicAdd(&sum[(size_t)s * 64 + l], res);
    if (l == 0) atomicAdd(&cnt[s], 1);
}

// out = sum / max(cnt,1); rows < n_items -> out_items chunk, rows >= n_items -> final chunk
__global__ void out_div_k(const float* __restrict__ sum, const int* __restrict__ cnt,
                          float* __restrict__ d_final, float* __restrict__ d_items,
                          int n_items, long total) {
    long idx = (long)blockIdx.x * blockDim.x + threadIdx.x;
    if (idx >= total) return;
    int i = (int)(idx >> 6);
    float v = sum[idx] / (float)max(cnt[i], 1);
    if (i < n_items) d_items[idx] = v;
    else             d_final[idx] = v;
}

// norm_all[j] = sum_d cat_nodes[j,d]^2 ; wave per node
__global__ void norm_k(const float* __restrict__ items, const float* __restrict__ user,
                       float* __restrict__ normv, int n_items, int N) {
    int j = blockIdx.x * (blockDim.x >> 6) + (threadIdx.x >> 6);
    if (j >= N) return;
    int l = threadIdx.x & 63;
    float c = (j < n_items) ? items[(size_t)j * 64 + l]
                            : user[(size_t)(j - n_items) * 64 + l];
    float s = wsum64(c * c);
    if (l == 0) normv[j] = s;
}

// item->user pass: accumulate cat_nodes[iu_src] at iu_dst (only user rows kept)
__global__ void iu_k(const float* __restrict__ items, const float* __restrict__ user,
                     const int* __restrict__ srcA, const int* __restrict__ dstA,
                     float* __restrict__ usum, int* __restrict__ ucnt,
                     int n_items, int N, int nE) {
    int e = blockIdx.x * (blockDim.x >> 6) + (threadIdx.x >> 6);
    if (e >= nE) return;
    int s = srcA[e], d = dstA[e];
    if (d < n_items || d >= N) return;       // only user slice is output
    int l = threadIdx.x & 63;
    float v = (s < n_items) ? items[(size_t)s * 64 + l]
                            : user[(size_t)(s - n_items) * 64 + l];
    atomicAdd(&usum[(size_t)(d - n_items) * 64 + l], v);
    if (l == 0) atomicAdd(&ucnt[d - n_items], 1);
}

// user->item pass: msg = cat[s]/(norm[s]+1e-6) * norm[d], accumulate at item d
__global__ void ui_k(const float* __restrict__ items, const float* __restrict__ user,
                     const float* __restrict__ normv,
                     const int* __restrict__ srcA, const int* __restrict__ dstA,
                     float* __restrict__ isum, int* __restrict__ icnt,
                     int n_items, int nE) {
    int e = blockIdx.x * (blockDim.x >> 6) + (threadIdx.x >> 6);
    if (e >= nE) return;
    int s = srcA[e], d = dstA[e];
    if (d >= n_items) return;                // only item slice is output
    int l = threadIdx.x & 63;
    float v = (s < n_items) ? items[(size_t)s * 64 + l]
                            : user[(size_t)(s - n_items) * 64 + l];
    float m = v / (normv[s] + 1e-6f) * normv[d];
    atomicAdd(&isum[(size_t)d * 64 + l], m);
    if (l == 0) atomicAdd(&icnt[d], 1);
}

__global__ void u_div_k(const float* __restrict__ usum, const int* __restrict__ ucnt,
                        float* __restrict__ uout, long total) {
    long idx = (long)blockIdx.x * blockDim.x + threadIdx.x;
    if (idx >= total) return;
    uout[idx] = usum[idx] / (float)max(ucnt[idx >> 6], 1);
}

// gate + fusion: gi = sigmoid(oi@W1.T + icf@W2.T); out = gi*oi + (1-gi)*icf
__global__ __launch_bounds__(256) void fusion_k(const float* __restrict__ items,
                         const float* __restrict__ isum, const int* __restrict__ icnt,
                         const float* __restrict__ W1, const float* __restrict__ W2,
                         float* __restrict__ outf, int n_items) {
    __shared__ float W1s[64][65];
    __shared__ float W2s[64][65];
    for (int idx = threadIdx.x; idx < 4096; idx += blockDim.x) {
        W1s[idx >> 6][idx & 63] = W1[idx];
        W2s[idx >> 6][idx & 63] = W2[idx];
    }
    __syncthreads();
    int i = blockIdx.x * (blockDim.x >> 6) + (threadIdx.x >> 6);
    if (i >= n_items) return;
    int j = threadIdx.x & 63;
    float oi = items[(size_t)i * 64 + j];
    float cf = isum[(size_t)i * 64 + j] / (float)max(icnt[i], 1);
    float acc = 0.f;
#pragma unroll 8
    for (int k = 0; k < 64; ++k) {
        acc += __shfl(oi, k) * W1s[j][k] + __shfl(cf, k) * W2s[j][k];
    }
    float g = 1.f / (1.f + expf(-acc));
    outf[(size_t)i * 64 + j] = g * oi + (1.f - g) * cf;
}

extern "C" void kernel_launch(void* const* d_in, const int* in_sizes, int n_in,
                              void* d_out, int out_size, void* d_ws, size_t ws_size,
                              hipStream_t stream) {
    const float* ent    = (const float*)d_in[0];
    const float* usr    = (const float*)d_in[1];
    const float* rel    = (const float*)d_in[2];
    const float* W1     = (const float*)d_in[3];
    const float* W2     = (const float*)d_in[4];
    const int*   kg_src = (const int*)d_in[5];
    const int*   kg_dst = (const int*)d_in[6];
    const int*   kg_typ = (const int*)d_in[7];
    const int*   iu_src = (const int*)d_in[8];
    const int*   iu_dst = (const int*)d_in[9];
    const int*   ui_src = (const int*)d_in[10];
    const int*   ui_dst = (const int*)d_in[11];

    const int n_ent   = in_sizes[0] / 64;
    const int n_usr   = in_sizes[1] / 64;
    const int E_kg    = in_sizes[5];
    const int E_iu    = in_sizes[8];
    const int E_ui    = in_sizes[10];
    const int n_items = (out_size - in_sizes[0] - in_sizes[1]) / 64;
    const int N       = n_items + n_usr;

    float* out_final = (float*)d_out;                        // (n_ent,64)
    float* out_u     = out_final + (size_t)n_ent * 64;       // (n_usr,64)
    float* out_items = out_u + (size_t)n_usr * 64;           // (n_items,64)

    // stash per-edge coefficients in d_out's first region (overwritten later by out_div_k)
    float4* coef = (float4*)d_out;                           // E_kg * 16B <= n_ent*64*4B

    float* ws = (float*)d_ws;
    size_t o = 0;
    float* sumkg = ws + o;          o += (size_t)n_ent * 64;
    int*   cntkg = (int*)(ws + o);  o += n_ent;
    float* usum  = ws + o;          size_t z2_start = o;
                                    o += (size_t)n_usr * 64;
    int*   ucnt  = (int*)(ws + o);  o += n_usr;
    float* isum  = ws + o;          o += (size_t)n_items * 64;
    int*   icnt  = (int*)(ws + o);  o += n_items;
    float* normv = ws + o;          o += N;
    size_t z2_len = ((size_t)n_usr * 65 + (size_t)n_items * 65) * sizeof(float);

    // zero KG accumulators (sum + cnt are contiguous)
    hipMemsetAsync(sumkg, 0, ((size_t)n_ent * 65) * sizeof(float), stream);

    kg_coef_k<<<(E_kg + 255) / 256, 256, 0, stream>>>(ent, rel, kg_src, kg_dst, kg_typ,
                                                      coef, E_kg);
    kg_out_k<<<(E_kg + 3) / 4, 256, 0, stream>>>(ent, rel, kg_src, kg_dst, kg_typ,
                                                 coef, sumkg, cntkg, E_kg);
    out_div_k<<<(int)(((size_t)n_ent * 64 + 255) / 256), 256, 0, stream>>>(
        sumkg, cntkg, out_final, out_items, n_items, (long)n_ent * 64);

    norm_k<<<(N + 3) / 4, 256, 0, stream>>>(out_items, usr, normv, n_items, N);

    // zero CF accumulators (usum,ucnt,isum,icnt contiguous)
    hipMemsetAsync(ws + z2_start, 0, z2_len, stream);

    iu_k<<<(E_iu + 3) / 4, 256, 0, stream>>>(out_items, usr, iu_src, iu_dst,
                                             usum, ucnt, n_items, N, E_iu);
    ui_k<<<(E_ui + 3) / 4, 256, 0, stream>>>(out_items, usr, normv, ui_src, ui_dst,
                                             isum, icnt, n_items, E_ui);
    u_div_k<<<(int)(((size_t)n_usr * 64 + 255) / 256), 256, 0, stream>>>(
        usum, ucnt, out_u, (long)n_usr * 64);
    fusion_k<<<(n_items + 3) / 4, 256, 0, stream>>>(out_items, isum, icnt,
                                                    W1, W2, out_final, n_items);
}

// Round 3
// 717.433 us; speedup vs baseline: 1.5576x; 1.0383x over previous
//
#include <hip/hip_runtime.h>
#include <cstdint>

#define EPSF 1e-15f
#define MAXN (1.0f - 1e-5f)

__device__ __forceinline__ float wsum64(float v) {
    v += __shfl_xor(v, 1);
    v += __shfl_xor(v, 2);
    v += __shfl_xor(v, 4);
    v += __shfl_xor(v, 8);
    v += __shfl_xor(v, 16);
    v += __shfl_xor(v, 32);
    return v;
}

// Fused KG kernel. Phase A (thread-per-edge): 6 raw dot products -> scalar
// hyperbolic chain -> coefficients (a,b,c) with res = a*u + b*v + c*r.
// a is folded into a per-src scalar accumulator (asum); (b,c) go to LDS.
// Phase B (wave-per-edge, 4-edge ILP): res_vec = b*v + c*r, atomic add at src.
__global__ __launch_bounds__(256) void kg_fused_k(const float* __restrict__ ent,
                           const float* __restrict__ rel,
                           const int* __restrict__ src,
                           const int* __restrict__ dst,
                           const int* __restrict__ typ,
                           float* __restrict__ sum,
                           float* __restrict__ asum,
                           float* __restrict__ cntf,
                           int nE) {
    __shared__ float sB[256], sC[256];
    __shared__ int sS[256], sD[256], sT[256];
    const int t = threadIdx.x;
    const int e0 = blockIdx.x << 8;
    const int e = e0 + t;

    if (e < nE) {
        int s = src[e], d = dst[e], ty = typ[e] + 2;
        const float4* pu = (const float4*)(ent + (size_t)s * 64);
        const float4* pv = (const float4*)(ent + (size_t)d * 64);
        const float4* pr = (const float4*)(rel + (size_t)ty * 64);

        float uu = 0.f, vv = 0.f, rr = 0.f, uv = 0.f, ur = 0.f, vr = 0.f;
#pragma unroll 4
        for (int i = 0; i < 16; ++i) {
            float4 a = pu[i], b = pv[i], c = pr[i];
            uu += a.x * a.x + a.y * a.y + a.z * a.z + a.w * a.w;
            vv += b.x * b.x + b.y * b.y + b.z * b.z + b.w * b.w;
            rr += c.x * c.x + c.y * c.y + c.z * c.z + c.w * c.w;
            uv += a.x * b.x + a.y * b.y + a.z * b.z + a.w * b.w;
            ur += a.x * c.x + a.y * c.y + a.z * c.z + a.w * c.w;
            vr += b.x * c.x + b.y * c.y + b.z * c.z + b.w * c.w;
        }

        // p = expmap0(u) = cp*u
        float n0 = sqrtf(fmaxf(uu, EPSF));
        float cp = tanhf(n0) / n0;
        float p2 = cp * cp * uu;
        float om_p2 = 1.f - p2;
        float lam = 2.f / fmaxf(om_p2, EPSF);

        // dh = expmap(v, p) = a1*u + b1*v
        float nv = sqrtf(fmaxf(vv, EPSF));
        float cd = tanhf(0.5f * lam * nv) / nv;
        float wd2 = cd * cd * vv;
        float pwd = cp * cd * uv;
        float Dd = fmaxf(1.f + 2.f * pwd + p2 * wd2, EPSF);
        float a1 = (1.f + 2.f * pwd + wd2) * cp / Dd;
        float b1 = om_p2 * cd / Dd;

        // rh = expmap(r, p) = a2*u + c2*r
        float nr = sqrtf(fmaxf(rr, EPSF));
        float cr = tanhf(0.5f * lam * nr) / nr;
        float wr2 = cr * cr * rr;
        float pwr = cp * cr * ur;
        float Dr = fmaxf(1.f + 2.f * pwr + p2 * wr2, EPSF);
        float a2 = (1.f + 2.f * pwr + wr2) * cp / Dr;
        float c2 = om_p2 * cr / Dr;

        // mobius_add(dh, rh): z = zu*u + zv*v + zr*r
        float x2 = a1 * a1 * uu + 2.f * a1 * b1 * uv + b1 * b1 * vv;
        float y2 = a2 * a2 * uu + 2.f * a2 * c2 * ur + c2 * c2 * rr;
        float xy = a1 * a2 * uu + a1 * c2 * ur + b1 * a2 * uv + b1 * c2 * vr;
        float den = fmaxf(1.f + 2.f * xy + x2 * y2, EPSF);
        float E = (1.f + 2.f * xy + y2) / den;
        float F = (1.f - x2) / den;
        float zu = E * a1 + F * a2;
        float zv = E * b1;
        float zr = F * c2;

        // project(z)
        float z2 = zu * zu * uu + zv * zv * vv + zr * zr * rr
                 + 2.f * (zu * zv * uv + zu * zr * ur + zv * zr * vr);
        float nz = sqrtf(fmaxf(z2, EPSF));
        if (nz > MAXN) {
            float sc = MAXN / nz;
            zu *= sc; zv *= sc; zr *= sc;
            z2 *= sc * sc;
        }

        // sub = mobius_add(-p, z) = su*u + sv*v + sr*r
        float mxy = -cp * (zu * uu + zv * uv + zr * ur);
        float denl = fmaxf(1.f + 2.f * mxy + p2 * z2, EPSF);
        float G = (1.f + 2.f * mxy + z2) / denl;
        float H = om_p2 / denl;
        float su = -G * cp + H * zu;
        float sv = H * zv;
        float sr = H * zr;

        float ns2 = su * su * uu + sv * sv * vv + sr * sr * rr
                  + 2.f * (su * sv * uv + su * sr * ur + sv * sr * vr);
        float ns = sqrtf(fmaxf(ns2, EPSF));
        float k = fmaxf(om_p2, EPSF) * atanhf(fminf(ns, MAXN)) / ns;

        sS[t] = s; sD[t] = d; sT[t] = ty;
        sB[t] = k * sv; sC[t] = k * sr;
        atomicAdd(&asum[s], k * su);
        atomicAdd(&cntf[s], 1.0f);
    } else {
        sS[t] = 0; sD[t] = 0; sT[t] = 0; sB[t] = 0.f; sC[t] = 0.f;
    }
    __syncthreads();

    const int w = t >> 6, l = t & 63;
#pragma unroll 4
    for (int k0 = 0; k0 < 64; k0 += 4) {
        float res[4]; int ss[4];
#pragma unroll
        for (int j = 0; j < 4; ++j) {
            int idx = (w << 6) + k0 + j;
            ss[j] = sS[idx];
            res[j] = sB[idx] * ent[(size_t)sD[idx] * 64 + l]
                   + sC[idx] * rel[(size_t)sT[idx] * 64 + l];
        }
#pragma unroll
        for (int j = 0; j < 4; ++j)
            atomicAdd(&sum[(size_t)ss[j] * 64 + l], res[j]);
    }
}

// out = (sum + asum*u) / max(cnt,1); rows < n_items -> out_items, else -> final chunk
__global__ void out_div_k(const float* __restrict__ sum, const float* __restrict__ asum,
                          const float* __restrict__ cntf, const float* __restrict__ ent,
                          float* __restrict__ d_final, float* __restrict__ d_items,
                          int n_items, long total) {
    long idx = (long)blockIdx.x * blockDim.x + threadIdx.x;
    if (idx >= total) return;
    int i = (int)(idx >> 6);
    float v = (sum[idx] + asum[i] * ent[idx]) / fmaxf(cntf[i], 1.f);
    if (i < n_items) d_items[idx] = v;
    else             d_final[idx] = v;
}

// norm_all[j] = sum_d cat_nodes[j,d]^2 ; wave per node
__global__ void norm_k(const float* __restrict__ items, const float* __restrict__ user,
                       float* __restrict__ normv, int n_items, int N) {
    int j = blockIdx.x * (blockDim.x >> 6) + (threadIdx.x >> 6);
    if (j >= N) return;
    int l = threadIdx.x & 63;
    float c = (j < n_items) ? items[(size_t)j * 64 + l]
                            : user[(size_t)(j - n_items) * 64 + l];
    float s = wsum64(c * c);
    if (l == 0) normv[j] = s;
}

// item->user pass, 4-edge ILP per wave
__global__ void iu_k(const float* __restrict__ items, const float* __restrict__ user,
                     const int* __restrict__ srcA, const int* __restrict__ dstA,
                     float* __restrict__ usum, float* __restrict__ ucnt,
                     int n_items, int N, int nE) {
    int w = blockIdx.x * (blockDim.x >> 6) + (threadIdx.x >> 6);
    int l = threadIdx.x & 63;
    int base = w * 4;
    float v[4]; int dd[4]; bool ok[4];
#pragma unroll
    for (int j = 0; j < 4; ++j) {
        int e = base + j;
        ok[j] = false; dd[j] = 0; v[j] = 0.f;
        if (e < nE) {
            int d = dstA[e];
            if (d >= n_items && d < N) {
                int s = srcA[e];
                ok[j] = true; dd[j] = d - n_items;
                v[j] = (s < n_items) ? items[(size_t)s * 64 + l]
                                     : user[(size_t)(s - n_items) * 64 + l];
            }
        }
    }
#pragma unroll
    for (int j = 0; j < 4; ++j) {
        if (ok[j]) {
            atomicAdd(&usum[(size_t)dd[j] * 64 + l], v[j]);
            if (l == 0) atomicAdd(&ucnt[dd[j]], 1.f);
        }
    }
}

// user->item pass, 4-edge ILP: msg = cat[s]/(norm[s]+1e-6) * norm[d]
__global__ void ui_k(const float* __restrict__ items, const float* __restrict__ user,
                     const float* __restrict__ normv,
                     const int* __restrict__ srcA, const int* __restrict__ dstA,
                     float* __restrict__ isum, float* __restrict__ icnt,
                     int n_items, int nE) {
    int w = blockIdx.x * (blockDim.x >> 6) + (threadIdx.x >> 6);
    int l = threadIdx.x & 63;
    int base = w * 4;
    float v[4]; int dd[4]; bool ok[4];
#pragma unroll
    for (int j = 0; j < 4; ++j) {
        int e = base + j;
        ok[j] = false; dd[j] = 0; v[j] = 0.f;
        if (e < nE) {
            int d = dstA[e];
            if (d < n_items) {
                int s = srcA[e];
                float f = normv[d] / (normv[s] + 1e-6f);
                ok[j] = true; dd[j] = d;
                float raw = (s < n_items) ? items[(size_t)s * 64 + l]
                                          : user[(size_t)(s - n_items) * 64 + l];
                v[j] = f * raw;
            }
        }
    }
#pragma unroll
    for (int j = 0; j < 4; ++j) {
        if (ok[j]) {
            atomicAdd(&isum[(size_t)dd[j] * 64 + l], v[j]);
            if (l == 0) atomicAdd(&icnt[dd[j]], 1.f);
        }
    }
}

__global__ void u_div_k(const float* __restrict__ usum, const float* __restrict__ ucnt,
                        float* __restrict__ uout, long total) {
    long idx = (long)blockIdx.x * blockDim.x + threadIdx.x;
    if (idx >= total) return;
    uout[idx] = usum[idx] / fmaxf(ucnt[idx >> 6], 1.f);
}

// gate + fusion: gi = sigmoid(oi@W1.T + icf@W2.T); out = gi*oi + (1-gi)*icf
__global__ __launch_bounds__(256) void fusion_k(const float* __restrict__ items,
                         const float* __restrict__ isum, const float* __restrict__ icnt,
                         const float* __restrict__ W1, const float* __restrict__ W2,
                         float* __restrict__ outf, int n_items) {
    __shared__ float W1s[64][65];
    __shared__ float W2s[64][65];
    for (int idx = threadIdx.x; idx < 4096; idx += blockDim.x) {
        W1s[idx >> 6][idx & 63] = W1[idx];
        W2s[idx >> 6][idx & 63] = W2[idx];
    }
    __syncthreads();
    int i = blockIdx.x * (blockDim.x >> 6) + (threadIdx.x >> 6);
    if (i >= n_items) return;
    int j = threadIdx.x & 63;
    float oi = items[(size_t)i * 64 + j];
    float cf = isum[(size_t)i * 64 + j] / fmaxf(icnt[i], 1.f);
    float acc = 0.f;
#pragma unroll 8
    for (int k = 0; k < 64; ++k) {
        acc += __shfl(oi, k) * W1s[j][k] + __shfl(cf, k) * W2s[j][k];
    }
    float g = 1.f / (1.f + expf(-acc));
    outf[(size_t)i * 64 + j] = g * oi + (1.f - g) * cf;
}

extern "C" void kernel_launch(void* const* d_in, const int* in_sizes, int n_in,
                              void* d_out, int out_size, void* d_ws, size_t ws_size,
                              hipStream_t stream) {
    const float* ent    = (const float*)d_in[0];
    const float* usr    = (const float*)d_in[1];
    const float* rel    = (const float*)d_in[2];
    const float* W1     = (const float*)d_in[3];
    const float* W2     = (const float*)d_in[4];
    const int*   kg_src = (const int*)d_in[5];
    const int*   kg_dst = (const int*)d_in[6];
    const int*   kg_typ = (const int*)d_in[7];
    const int*   iu_src = (const int*)d_in[8];
    const int*   iu_dst = (const int*)d_in[9];
    const int*   ui_src = (const int*)d_in[10];
    const int*   ui_dst = (const int*)d_in[11];

    const int n_ent   = in_sizes[0] / 64;
    const int n_usr   = in_sizes[1] / 64;
    const int E_kg    = in_sizes[5];
    const int E_iu    = in_sizes[8];
    const int E_ui    = in_sizes[10];
    const int n_items = (out_size - in_sizes[0] - in_sizes[1]) / 64;
    const int N       = n_items + n_usr;

    float* out_final = (float*)d_out;                        // (n_ent,64)
    float* out_u     = out_final + (size_t)n_ent * 64;       // (n_usr,64)
    float* out_items = out_u + (size_t)n_usr * 64;           // (n_items,64)

    float* ws = (float*)d_ws;
    size_t o = 0;
    float* sumkg = ws + o;          o += (size_t)n_ent * 64;
    float* asum  = ws + o;          o += n_ent;
    float* cntkg = ws + o;          o += n_ent;
    float* usum  = ws + o;          size_t z2_start = o;
                                    o += (size_t)n_usr * 64;
    float* ucnt  = ws + o;          o += n_usr;
    float* isum  = ws + o;          o += (size_t)n_items * 64;
    float* icnt  = ws + o;          o += n_items;
    float* normv = ws + o;          o += N;
    size_t z2_len = ((size_t)n_usr * 65 + (size_t)n_items * 65) * sizeof(float);

    // zero KG accumulators (sum + asum + cnt are contiguous)
    hipMemsetAsync(sumkg, 0, ((size_t)n_ent * 66) * sizeof(float), stream);

    kg_fused_k<<<(E_kg + 255) / 256, 256, 0, stream>>>(ent, rel, kg_src, kg_dst, kg_typ,
                                                       sumkg, asum, cntkg, E_kg);
    out_div_k<<<(int)(((size_t)n_ent * 64 + 255) / 256), 256, 0, stream>>>(
        sumkg, asum, cntkg, ent, out_final, out_items, n_items, (long)n_ent * 64);

    norm_k<<<(N + 3) / 4, 256, 0, stream>>>(out_items, usr, normv, n_items, N);

    // zero CF accumulators (usum,ucnt,isum,icnt contiguous)
    hipMemsetAsync(ws + z2_start, 0, z2_len, stream);

    iu_k<<<(E_iu + 15) / 16, 256, 0, stream>>>(out_items, usr, iu_src, iu_dst,
                                               usum, ucnt, n_items, N, E_iu);
    ui_k<<<(E_ui + 15) / 16, 256, 0, stream>>>(out_items, usr, normv, ui_src, ui_dst,
                                               isum, icnt, n_items, E_ui);
    u_div_k<<<(int)(((size_t)n_usr * 64 + 255) / 256), 256, 0, stream>>>(
        usum, ucnt, out_u, (long)n_usr * 64);
    fusion_k<<<(n_items + 3) / 4, 256, 0, stream>>>(out_items, isum, icnt,
                                                    W1, W2, out_final, n_items);
}